// Round 1
// baseline (194.931 us; speedup 1.0000x reference)
//
#include <hip/hip_runtime.h>
#include <hip/hip_bf16.h>

// Problem constants: B=8, NH=8, KS=VS=64, HW=1024, C=1536, NUM_GROUPS=24
#define LDW 72   // 64 + 8 pad (bf16 elems) -> row stride 144 B, 16B-aligned

typedef __attribute__((ext_vector_type(8))) short bf16x8;
typedef __attribute__((ext_vector_type(4))) float f32x4;

__device__ __forceinline__ short f2bf(float f) {
    union { float f; unsigned u; } a; a.f = f;
    unsigned u = a.u;
    return (short)((u + 0x7fffu + ((u >> 16) & 1u)) >> 16);  // RNE
}

// ---- Kernel 1: GroupNorm stats. One block per (b,group); each group is a
// contiguous 64ch*1024 = 65536-float chunk. Writes mean,rstd to ws.
__global__ __launch_bounds__(256) void gn_stats(const float* __restrict__ x,
                                                float* __restrict__ stats) {
    int bg = blockIdx.x;                       // 0..191
    const float4* p = (const float4*)(x + (size_t)bg * 65536);
    float s1 = 0.f, s2 = 0.f;
    for (int i = threadIdx.x; i < 16384; i += 256) {
        float4 v = p[i];
        s1 += v.x + v.y + v.z + v.w;
        s2 += v.x*v.x + v.y*v.y + v.z*v.z + v.w*v.w;
    }
    for (int off = 32; off > 0; off >>= 1) {
        s1 += __shfl_down(s1, off);
        s2 += __shfl_down(s2, off);
    }
    __shared__ float a1[4], a2[4];
    int wave = threadIdx.x >> 6, lane = threadIdx.x & 63;
    if (lane == 0) { a1[wave] = s1; a2[wave] = s2; }
    __syncthreads();
    if (threadIdx.x == 0) {
        float t1 = a1[0] + a1[1] + a1[2] + a1[3];
        float t2 = a2[0] + a2[1] + a2[2] + a2[3];
        float mean = t1 * (1.f / 65536.f);
        float var  = t2 * (1.f / 65536.f) - mean * mean;
        stats[bg * 2 + 0] = mean;
        stats[bg * 2 + 1] = rsqrtf(var + 1e-5f);
    }
}

// ---- Kernel 2: fused GN-apply + flash attention.
// Grid: (qtile 0..15, pair 0..63). Block: 256 threads = 4 waves.
// Each wave owns 16 queries of the 64-query tile.
__global__ __launch_bounds__(256) void attn_kernel(
    const float* __restrict__ x, const float* __restrict__ gamma,
    const float* __restrict__ beta, const float* __restrict__ stats,
    float* __restrict__ out)
{
    const int qtile = blockIdx.x;   // 0..15
    const int pair  = blockIdx.y;   // 0..63
    const int b = pair >> 3, h = pair & 7;

    const int tid  = threadIdx.x;
    const int wave = tid >> 6;
    const int lane = tid & 63;
    const int grp  = lane >> 4;     // quad-of-16 within wave
    const int li   = lane & 15;

    __shared__ alignas(16) short Qt[64][LDW];      // [q][c]  (Q^T)
    __shared__ alignas(16) short Kt[64][LDW];      // [k][c]  (K^T)
    __shared__ alignas(16) short Vt[64][LDW];      // [v][k]
    __shared__ alignas(16) short Pt[4][16][LDW];   // per-wave P [q_local][k]

    const float* xb = x + (size_t)b * 1536 * 1024;

    const int gk = 3 * h, gq = 3 * h + 1, gv = 3 * h + 2;
    const float mean_k = stats[(b * 24 + gk) * 2 + 0];
    const float rstd_k = stats[(b * 24 + gk) * 2 + 1];
    const float mean_q = stats[(b * 24 + gq) * 2 + 0];
    const float rstd_q = stats[(b * 24 + gq) * 2 + 1];
    const float mean_v = stats[(b * 24 + gv) * 2 + 0];
    const float rstd_v = stats[(b * 24 + gv) * 2 + 1];

    // ---- stage normalized Q tile (channels h*192+64.., queries qtile*64..)
    for (int i = tid; i < 1024; i += 256) {
        int c = i >> 4;
        int s = (i & 15) << 2;
        int cg = h * 192 + 64 + c;
        float4 v = *(const float4*)(xb + (size_t)cg * 1024 + qtile * 64 + s);
        float w  = gamma[cg] * rstd_q;
        float bb = beta[cg] - mean_q * w;
        Qt[s + 0][c] = f2bf(v.x * w + bb);
        Qt[s + 1][c] = f2bf(v.y * w + bb);
        Qt[s + 2][c] = f2bf(v.z * w + bb);
        Qt[s + 3][c] = f2bf(v.w * w + bb);
    }
    __syncthreads();

    // A-frags for Q (loop-invariant): A[m=li][k=ch*32+grp*8+j]
    bf16x8 aq0 = *(const bf16x8*)&Qt[wave * 16 + li][grp * 8];
    bf16x8 aq1 = *(const bf16x8*)&Qt[wave * 16 + li][32 + grp * 8];

    f32x4 oacc[4];
    for (int vf = 0; vf < 4; ++vf) oacc[vf] = f32x4{0.f, 0.f, 0.f, 0.f};
    float mrun[4] = {-1e30f, -1e30f, -1e30f, -1e30f};
    float lrun[4] = {0.f, 0.f, 0.f, 0.f};

    for (int kt = 0; kt < 16; ++kt) {
        __syncthreads();   // prior iter's Kt/Vt/Pt reads complete
        // ---- stage normalized K (as [k][c]) and V (as [v][k]) tiles
        for (int i = tid; i < 1024; i += 256) {
            int c = i >> 4;
            int s = (i & 15) << 2;
            {
                int cg = h * 192 + c;
                float4 v = *(const float4*)(xb + (size_t)cg * 1024 + kt * 64 + s);
                float w  = gamma[cg] * rstd_k;
                float bb = beta[cg] - mean_k * w;
                Kt[s + 0][c] = f2bf(v.x * w + bb);
                Kt[s + 1][c] = f2bf(v.y * w + bb);
                Kt[s + 2][c] = f2bf(v.z * w + bb);
                Kt[s + 3][c] = f2bf(v.w * w + bb);
            }
            {
                int cg = h * 192 + 128 + c;
                float4 v = *(const float4*)(xb + (size_t)cg * 1024 + kt * 64 + s);
                float w  = gamma[cg] * rstd_v;
                float bb = beta[cg] - mean_v * w;
                Vt[c][s + 0] = f2bf(v.x * w + bb);
                Vt[c][s + 1] = f2bf(v.y * w + bb);
                Vt[c][s + 2] = f2bf(v.z * w + bb);
                Vt[c][s + 3] = f2bf(v.w * w + bb);
            }
        }
        __syncthreads();

        // ---- S = Q^T K : this wave's 16 queries x 64 keys (4 frags)
        f32x4 sf[4];
        for (int f = 0; f < 4; ++f) {
            f32x4 acc = f32x4{0.f, 0.f, 0.f, 0.f};
            bf16x8 b0 = *(const bf16x8*)&Kt[f * 16 + li][grp * 8];
            acc = __builtin_amdgcn_mfma_f32_16x16x32_bf16(aq0, b0, acc, 0, 0, 0);
            bf16x8 b1 = *(const bf16x8*)&Kt[f * 16 + li][32 + grp * 8];
            acc = __builtin_amdgcn_mfma_f32_16x16x32_bf16(aq1, b1, acc, 0, 0, 0);
            sf[f] = acc;
        }

        // ---- online softmax. C-layout: row(query)=grp*4+r, col(key)=f*16+li
        float mx[4];
        for (int r = 0; r < 4; ++r) {
            float m0 = fmaxf(fmaxf(sf[0][r], sf[1][r]), fmaxf(sf[2][r], sf[3][r]));
            mx[r] = m0 * 0.125f;   // scale by 1/sqrt(64); positive so max commutes
        }
        for (int off = 1; off < 16; off <<= 1)
            for (int r = 0; r < 4; ++r)
                mx[r] = fmaxf(mx[r], __shfl_xor(mx[r], off));

        float alpha[4], mnew[4], sum[4];
        for (int r = 0; r < 4; ++r) {
            mnew[r]  = fmaxf(mrun[r], mx[r]);
            alpha[r] = __expf(mrun[r] - mnew[r]);
            mrun[r]  = mnew[r];
            sum[r]   = 0.f;
        }
        for (int f = 0; f < 4; ++f) {
            for (int r = 0; r < 4; ++r) {
                float p = __expf(sf[f][r] * 0.125f - mnew[r]);
                sum[r] += p;
                Pt[wave][grp * 4 + r][f * 16 + li] = f2bf(p);
            }
        }
        for (int off = 1; off < 16; off <<= 1)
            for (int r = 0; r < 4; ++r)
                sum[r] += __shfl_xor(sum[r], off);
        for (int r = 0; r < 4; ++r) lrun[r] = lrun[r] * alpha[r] + sum[r];
        for (int vf = 0; vf < 4; ++vf)
            for (int r = 0; r < 4; ++r)
                oacc[vf][r] *= alpha[r];

        __syncthreads();   // make Pt stores visible before A-frag reads (safety)

        // ---- O += P * V^T : A = P (m=q, k=key), B = V^T (k=key, n=vrow)
        for (int ch = 0; ch < 2; ++ch) {
            bf16x8 ap = *(const bf16x8*)&Pt[wave][li][ch * 32 + grp * 8];
            for (int vf = 0; vf < 4; ++vf) {
                bf16x8 bv = *(const bf16x8*)&Vt[vf * 16 + li][ch * 32 + grp * 8];
                oacc[vf] = __builtin_amdgcn_mfma_f32_16x16x32_bf16(ap, bv, oacc[vf], 0, 0, 0);
            }
        }
    }

    // ---- epilogue: O /= l; write out[b][h*64+vrow][q]
    float inv[4];
    for (int r = 0; r < 4; ++r) inv[r] = 1.f / lrun[r];
    float* ob = out + (size_t)pair * 64 * 1024;
    for (int vf = 0; vf < 4; ++vf) {
        int vrow = vf * 16 + li;
        for (int r = 0; r < 4; ++r) {
            int q = qtile * 64 + wave * 16 + grp * 4 + r;
            ob[(size_t)vrow * 1024 + q] = oacc[vf][r] * inv[r];
        }
    }
}

extern "C" void kernel_launch(void* const* d_in, const int* in_sizes, int n_in,
                              void* d_out, int out_size, void* d_ws, size_t ws_size,
                              hipStream_t stream) {
    const float* x     = (const float*)d_in[0];
    const float* gamma = (const float*)d_in[1];
    const float* beta  = (const float*)d_in[2];
    float* out   = (float*)d_out;
    float* stats = (float*)d_ws;   // 192 * 2 floats

    gn_stats<<<192, 256, 0, stream>>>(x, stats);
    attn_kernel<<<dim3(16, 64), 256, 0, stream>>>(x, gamma, beta, stats, out);
}

// Round 2
// 165.763 us; speedup vs baseline: 1.1760x; 1.1760x over previous
//
#include <hip/hip_runtime.h>
#include <hip/hip_bf16.h>

// B=8, NH=8, KS=VS=64, HW=1024, C=1536, GROUPS=24. pair = b*8+h (64 pairs).
// Pipeline: gn_partial -> gn_final -> pack(bf16 Qn/Kn [s][c], Vn [c][s]) -> attn.

typedef __attribute__((ext_vector_type(8))) short bf16x8;
typedef __attribute__((ext_vector_type(4))) float f32x4;
typedef unsigned short u16;

__device__ __forceinline__ u16 f2bf(float f) {
    union { float f; unsigned u; } a; a.f = f;
    unsigned u = a.u;
    return (u16)((u + 0x7fffu + ((u >> 16) & 1u)) >> 16);  // RNE
}

// ---- Kernel 1: partial GN stats. 1536 blocks = 8 slices per (b,group).
__global__ __launch_bounds__(256) void gn_partial(const float* __restrict__ x,
                                                  float* __restrict__ partials) {
    int blk = blockIdx.x;                         // 0..1535
    const float4* p = (const float4*)(x + (size_t)blk * 8192);
    int t = threadIdx.x;
    float s1a = 0.f, s2a = 0.f, s1b = 0.f, s2b = 0.f;
#pragma unroll
    for (int i = 0; i < 8; i += 2) {
        float4 va = p[t + i * 256];
        float4 vb = p[t + (i + 1) * 256];
        s1a += va.x + va.y + va.z + va.w;
        s2a += va.x * va.x + va.y * va.y + va.z * va.z + va.w * va.w;
        s1b += vb.x + vb.y + vb.z + vb.w;
        s2b += vb.x * vb.x + vb.y * vb.y + vb.z * vb.z + vb.w * vb.w;
    }
    float s1 = s1a + s1b, s2 = s2a + s2b;
    for (int off = 32; off > 0; off >>= 1) {
        s1 += __shfl_down(s1, off);
        s2 += __shfl_down(s2, off);
    }
    __shared__ float a1[4], a2[4];
    int wave = t >> 6, lane = t & 63;
    if (lane == 0) { a1[wave] = s1; a2[wave] = s2; }
    __syncthreads();
    if (t == 0) {
        partials[blk * 2 + 0] = a1[0] + a1[1] + a1[2] + a1[3];
        partials[blk * 2 + 1] = a2[0] + a2[1] + a2[2] + a2[3];
    }
}

// ---- Kernel 2: finalize mean/rstd for 192 (b,group) pairs.
__global__ __launch_bounds__(256) void gn_final(const float* __restrict__ partials,
                                                float* __restrict__ stats) {
    int t = threadIdx.x;
    if (t < 192) {
        float s1 = 0.f, s2 = 0.f;
#pragma unroll
        for (int j = 0; j < 8; ++j) {
            s1 += partials[(t * 8 + j) * 2 + 0];
            s2 += partials[(t * 8 + j) * 2 + 1];
        }
        float mean = s1 * (1.f / 65536.f);
        float var  = s2 * (1.f / 65536.f) - mean * mean;
        stats[t * 2 + 0] = mean;
        stats[t * 2 + 1] = rsqrtf(var + 1e-5f);
    }
}

// ---- Kernel 3: normalize + bf16 pack. Qn,Kn: [pair][s=1024][c=64] (transposed
// via 4x4 register blocks); Vn: [pair][c=64][s=1024] (native). Grid (16,64).
__global__ __launch_bounds__(256) void pack_kernel(
    const float* __restrict__ x, const float* __restrict__ gamma,
    const float* __restrict__ beta, const float* __restrict__ stats,
    u16* __restrict__ Qn, u16* __restrict__ Kn, u16* __restrict__ Vn)
{
    const int st = blockIdx.x, pair = blockIdx.y;
    const int b = pair >> 3, h = pair & 7;
    const float* xb = x + (size_t)b * 1536 * 1024;
    const int g0 = (b * 24 + 3 * h) * 2;
    const float mk = stats[g0 + 0], rk = stats[g0 + 1];
    const float mq = stats[g0 + 2], rq = stats[g0 + 3];
    const float mv = stats[g0 + 4], rv = stats[g0 + 5];

    const int t = threadIdx.x;
    const int c0 = (t >> 4) * 4;        // 0..60
    const int s4 = (t & 15) * 4;        // 0..60
    const int sg = st * 64 + s4;

    // K (t2=0) and Q (t2=1): 4x4 register-block transpose, no LDS.
#pragma unroll
    for (int t2 = 0; t2 < 2; ++t2) {
        const int cb = h * 192 + t2 * 64;
        const float mean = t2 ? mq : mk;
        const float rstd = t2 ? rq : rk;
        u16* dst = t2 ? Qn : Kn;
        float4 rr[4];
#pragma unroll
        for (int dc = 0; dc < 4; ++dc) {
            int cg = cb + c0 + dc;
            float4 vv = *(const float4*)(xb + (size_t)cg * 1024 + sg);
            float wsc = gamma[cg] * rstd;
            float bsc = beta[cg] - mean * wsc;
            rr[dc].x = vv.x * wsc + bsc; rr[dc].y = vv.y * wsc + bsc;
            rr[dc].z = vv.z * wsc + bsc; rr[dc].w = vv.w * wsc + bsc;
        }
        u16* dp = dst + (size_t)pair * 65536 + (size_t)sg * 64 + c0;
        ushort4 o;
        o.x = f2bf(rr[0].x); o.y = f2bf(rr[1].x); o.z = f2bf(rr[2].x); o.w = f2bf(rr[3].x);
        *(ushort4*)(dp +   0) = o;
        o.x = f2bf(rr[0].y); o.y = f2bf(rr[1].y); o.z = f2bf(rr[2].y); o.w = f2bf(rr[3].y);
        *(ushort4*)(dp +  64) = o;
        o.x = f2bf(rr[0].z); o.y = f2bf(rr[1].z); o.z = f2bf(rr[2].z); o.w = f2bf(rr[3].z);
        *(ushort4*)(dp + 128) = o;
        o.x = f2bf(rr[0].w); o.y = f2bf(rr[1].w); o.z = f2bf(rr[2].w); o.w = f2bf(rr[3].w);
        *(ushort4*)(dp + 192) = o;
    }

    // V: native layout, pure elementwise.
#pragma unroll
    for (int p = 0; p < 4; ++p) {
        int c = p * 16 + (t >> 4);
        int cg = h * 192 + 128 + c;
        float4 vv = *(const float4*)(xb + (size_t)cg * 1024 + sg);
        float wsc = gamma[cg] * rv;
        float bsc = beta[cg] - mv * wsc;
        ushort4 o;
        o.x = f2bf(vv.x * wsc + bsc); o.y = f2bf(vv.y * wsc + bsc);
        o.z = f2bf(vv.z * wsc + bsc); o.w = f2bf(vv.w * wsc + bsc);
        *(ushort4*)(Vn + (size_t)pair * 65536 + (size_t)c * 1024 + sg) = o;
    }
}

// ---- Kernel 4: flash attention, barrier-free. Grid (8,64), 256 thr = 4 waves.
// Each wave owns 32 queries; K/V/Q frags loaded directly from global (L1/L2-hot);
// only P (and the O epilogue transpose) go through wave-private LDS.
__global__ __launch_bounds__(256) void attn_kernel(
    const u16* __restrict__ Qn, const u16* __restrict__ Kn,
    const u16* __restrict__ Vn, float* __restrict__ out)
{
    const int qt = blockIdx.x;      // 0..7
    const int pair = blockIdx.y;    // 0..63
    const int tid = threadIdx.x;
    const int w = tid >> 6;
    const int lane = tid & 63;
    const int grp = lane >> 4;
    const int li  = lane & 15;

    __shared__ alignas(16) u16  Pt[4][2][16][72];   // per-wave P [qf][q_local][k]
    __shared__ alignas(16) float Ot[4][64][36];     // per-wave O [v][q_local]

    const u16* Qp = Qn + (size_t)pair * 65536;
    const u16* Kp = Kn + (size_t)pair * 65536;
    const u16* Vp = Vn + (size_t)pair * 65536;
    const int qbase = qt * 128 + w * 32;

    // Q A-frags (loop-invariant): A[m=li][k=hf*32+grp*8+j]
    bf16x8 aq[2][2];
#pragma unroll
    for (int qf = 0; qf < 2; ++qf)
#pragma unroll
        for (int hf = 0; hf < 2; ++hf)
            aq[qf][hf] = *(const bf16x8*)(Qp + (size_t)(qbase + qf * 16 + li) * 64 + hf * 32 + grp * 8);

    f32x4 oacc[2][4];
    float mrun[2][4], lrun[2][4];
#pragma unroll
    for (int qf = 0; qf < 2; ++qf) {
#pragma unroll
        for (int vf = 0; vf < 4; ++vf) oacc[qf][vf] = f32x4{0.f, 0.f, 0.f, 0.f};
#pragma unroll
        for (int r = 0; r < 4; ++r) { mrun[qf][r] = -1e30f; lrun[qf][r] = 0.f; }
    }

    for (int kt = 0; kt < 16; ++kt) {
        // K B-frags: B[n=li][k], rows = keys kt*64 + f*16+li
        const u16* Kt0 = Kp + (size_t)(kt * 64) * 64;
        bf16x8 bk[4][2];
#pragma unroll
        for (int f = 0; f < 4; ++f)
#pragma unroll
            for (int hf = 0; hf < 2; ++hf)
                bk[f][hf] = *(const bf16x8*)(Kt0 + (size_t)(f * 16 + li) * 64 + hf * 32 + grp * 8);

        // V B-frags: rows = v-channels vf*16+li, k = keys kt*64 + ...
        bf16x8 bv[4][2];
#pragma unroll
        for (int vf = 0; vf < 4; ++vf)
#pragma unroll
            for (int hf = 0; hf < 2; ++hf)
                bv[vf][hf] = *(const bf16x8*)(Vp + (size_t)(vf * 16 + li) * 1024 + kt * 64 + hf * 32 + grp * 8);

        // S = Q^T K
        f32x4 sf[2][4];
#pragma unroll
        for (int qf = 0; qf < 2; ++qf)
#pragma unroll
            for (int f = 0; f < 4; ++f) {
                f32x4 acc = f32x4{0.f, 0.f, 0.f, 0.f};
                acc = __builtin_amdgcn_mfma_f32_16x16x32_bf16(aq[qf][0], bk[f][0], acc, 0, 0, 0);
                acc = __builtin_amdgcn_mfma_f32_16x16x32_bf16(aq[qf][1], bk[f][1], acc, 0, 0, 0);
                sf[qf][f] = acc;
            }

        // online softmax (C-layout: row=grp*4+r, col=f*16+li), then PV
#pragma unroll
        for (int qf = 0; qf < 2; ++qf) {
            float mx[4];
#pragma unroll
            for (int r = 0; r < 4; ++r) {
                float m0 = fmaxf(fmaxf(sf[qf][0][r], sf[qf][1][r]),
                                 fmaxf(sf[qf][2][r], sf[qf][3][r]));
                mx[r] = m0 * 0.125f;
            }
#pragma unroll
            for (int off = 1; off < 16; off <<= 1)
#pragma unroll
                for (int r = 0; r < 4; ++r)
                    mx[r] = fmaxf(mx[r], __shfl_xor(mx[r], off));

            float mnew[4], alpha[4], sum[4];
#pragma unroll
            for (int r = 0; r < 4; ++r) {
                mnew[r]  = fmaxf(mrun[qf][r], mx[r]);
                alpha[r] = __expf(mrun[qf][r] - mnew[r]);
                mrun[qf][r] = mnew[r];
                sum[r] = 0.f;
            }
#pragma unroll
            for (int f = 0; f < 4; ++f)
#pragma unroll
                for (int r = 0; r < 4; ++r) {
                    float p = __expf(sf[qf][f][r] * 0.125f - mnew[r]);
                    sum[r] += p;
                    Pt[w][qf][grp * 4 + r][f * 16 + li] = f2bf(p);
                }
#pragma unroll
            for (int off = 1; off < 16; off <<= 1)
#pragma unroll
                for (int r = 0; r < 4; ++r)
                    sum[r] += __shfl_xor(sum[r], off);
#pragma unroll
            for (int r = 0; r < 4; ++r)
                lrun[qf][r] = lrun[qf][r] * alpha[r] + sum[r];
#pragma unroll
            for (int vf = 0; vf < 4; ++vf)
#pragma unroll
                for (int r = 0; r < 4; ++r)
                    oacc[qf][vf][r] *= alpha[r];

            // O += P * V^T  (wave-private LDS round-trip, no barrier needed)
#pragma unroll
            for (int ch = 0; ch < 2; ++ch) {
                bf16x8 ap = *(const bf16x8*)&Pt[w][qf][li][ch * 32 + grp * 8];
#pragma unroll
                for (int vf = 0; vf < 4; ++vf)
                    oacc[qf][vf] = __builtin_amdgcn_mfma_f32_16x16x32_bf16(ap, bv[vf][ch], oacc[qf][vf], 0, 0, 0);
            }
        }
    }

    // epilogue: divide by l, transpose via LDS, coalesced float4 stores
#pragma unroll
    for (int qf = 0; qf < 2; ++qf) {
        float inv[4];
#pragma unroll
        for (int r = 0; r < 4; ++r) inv[r] = 1.f / lrun[qf][r];
#pragma unroll
        for (int vf = 0; vf < 4; ++vf)
#pragma unroll
            for (int r = 0; r < 4; ++r)
                Ot[w][vf * 16 + li][qf * 16 + grp * 4 + r] = oacc[qf][vf][r] * inv[r];
    }
    float* ob = out + (size_t)pair * 65536 + qbase;
    const int r8 = lane >> 3, c8 = lane & 7;
#pragma unroll
    for (int p = 0; p < 8; ++p) {
        int v = p * 8 + r8;
        float4 o4 = *(float4*)&Ot[w][v][c8 * 4];
        *(float4*)(ob + (size_t)v * 1024 + c8 * 4) = o4;
    }
}

extern "C" void kernel_launch(void* const* d_in, const int* in_sizes, int n_in,
                              void* d_out, int out_size, void* d_ws, size_t ws_size,
                              hipStream_t stream) {
    const float* x     = (const float*)d_in[0];
    const float* gamma = (const float*)d_in[1];
    const float* beta  = (const float*)d_in[2];
    float* out = (float*)d_out;

    float* stats    = (float*)d_ws;                       // 384 f32
    float* partials = (float*)d_ws + 1024;                // 3072 f32 @ +4KB
    u16* Qn = (u16*)((char*)d_ws + 16384);                // 8 MB
    u16* Kn = Qn + (size_t)64 * 65536;                    // 8 MB
    u16* Vn = Kn + (size_t)64 * 65536;                    // 8 MB (total ~25.2 MB)

    gn_partial<<<1536, 256, 0, stream>>>(x, partials);
    gn_final<<<1, 256, 0, stream>>>(partials, stats);
    pack_kernel<<<dim3(16, 64), 256, 0, stream>>>(x, gamma, beta, stats, Qn, Kn, Vn);
    attn_kernel<<<dim3(8, 64), 256, 0, stream>>>(Qn, Kn, Vn, out);
}